// Round 19
// baseline (447.418 us; speedup 1.0000x reference)
//
#include <hip/hip_runtime.h>
#include <hip/hip_bf16.h>

// EGNN forward — r18 + ONE change: k_edge processes 2 ADJACENT groups per wave
// with phase-interleaved duplicated state (intra-wave ILP fills dependency
// stalls; no pipe was saturated: VALU 28%, LDS ~38%, MFMA 5%, HBM 12%).
// Register audit: ~35 live VGPR/group on 60-VGPR base => ~110 total < 128
// (r8's spill came from doubling an 84-base). LDS 46.6KB => 3 blocks/CU.
// Pipeline: k_prep -> k_gab(+hist) -> k_scanA -> k_scanC -> k_scatter(+cdr)
//   -> k_edge -> k_node.
// ws: agg_m[N*64]f | agg_x[N*3]f | deg[N]i | WA[2048]f | WB[2048]f | WF1[2048]f
//   | Wno[4096]f | bSum[64]f | bn1f[64]f | bno[64]f | rowNext[N]i | bsumBuf[512]i
//   | cdr[E]f32x4 | srt8[E]u64 | nfb[N*32]bf16
// d_out: out[N*64] | coords_out[N*3]; doubles as bf16 gA/gB scratch.
//
// Locked: (r3) shfl in uniform flow; (r6,r10) no bounds(,4)/persistent frags;
// (r13) weights in LDS; (r14) 16-edge tile; (r16) cvt_pk; (r17) cdr precompute;
// (r18) stride-76 pad. Spill tripwire: WRITE_SIZE must stay ~49MB.

typedef __attribute__((ext_vector_type(4))) float f32x4;
typedef __attribute__((ext_vector_type(8))) short short8;

__device__ __forceinline__ void atomAddF(float* p, float v) { unsafeAtomicAdd(p, v); }

__device__ __forceinline__ unsigned int pack2bf(float lo, float hi) {
  unsigned int r;
  asm("v_cvt_pk_bf16_f32 %0, %1, %2" : "=v"(r) : "v"(lo), "v"(hi));
  return r;  // lo -> bits [15:0], hi -> bits [31:16]
}
__device__ __forceinline__ unsigned short f2bf(float f) {
  return (unsigned short)(pack2bf(f, 0.f) & 0xFFFFu);
}
__device__ __forceinline__ float bf2f(unsigned short s) {
  unsigned int v = ((unsigned int)s) << 16;
  return __builtin_bit_cast(float, v);
}
__device__ __forceinline__ float lo_bf(unsigned int u) {
  return __builtin_bit_cast(float, u << 16);
}
__device__ __forceinline__ float hi_bf(unsigned int u) {
  return __builtin_bit_cast(float, u & 0xFFFF0000u);
}

// ---------------- k_prep: folds + nf->bf16 + agg/deg zero ----------------
__global__ __launch_bounds__(256) void k_prep(
    const float* __restrict__ nf, const float* __restrict__ W_in,
    const float* __restrict__ b_in, const float* __restrict__ We1,
    const float* __restrict__ be1, const float* __restrict__ Wn1,
    const float* __restrict__ bn1, const float* __restrict__ Wn2,
    const float* __restrict__ bn2, const float* __restrict__ W_out,
    const float* __restrict__ b_out, unsigned short* __restrict__ nfb,
    float* __restrict__ WA, float* __restrict__ WB, float* __restrict__ WF1,
    float* __restrict__ Wno, float* __restrict__ bSum, float* __restrict__ bn1f,
    float* __restrict__ bno, float* __restrict__ aggz, int N) {
  const int b = blockIdx.x, t = threadIdx.x;
  if (b == 0 || b == 1) {
    const float* Wsrc = (b == 0) ? We1 : (We1 + 64 * 64);
    float* dst = (b == 0) ? WA : WB;
    for (int idx = t; idx < 2048; idx += 256) {
      const int i = idx >> 6, n = idx & 63;
      float s = 0.f;
      for (int h = 0; h < 64; ++h) s = fmaf(W_in[i * 64 + h], Wsrc[h * 64 + n], s);
      dst[idx] = s;
    }
  } else if (b == 2) {
    for (int idx = t; idx < 2048; idx += 256) {
      const int i = idx >> 6, n = idx & 63;
      float s = 0.f;
      for (int h = 0; h < 64; ++h) s = fmaf(W_in[i * 64 + h], Wn1[h * 64 + n], s);
      WF1[idx] = s;
    }
    if (t < 64) {
      float s1 = bn1[t], s2 = be1[t];
      for (int h = 0; h < 64; ++h) {
        s1 = fmaf(b_in[h], Wn1[h * 64 + t], s1);
        s2 = fmaf(b_in[h], We1[h * 64 + t] + We1[(64 + h) * 64 + t], s2);
      }
      bn1f[t] = s1;
      bSum[t] = s2;
    }
  } else if (b <= 6) {
    const int base = (b - 3) * 1024;
    for (int idx = t; idx < 1024; idx += 256) {
      const int kk = (base + idx) >> 6, n = (base + idx) & 63;
      float s = 0.f;
      for (int h = 0; h < 64; ++h) s = fmaf(Wn2[kk * 64 + h], W_out[h * 64 + n], s);
      Wno[base + idx] = s;
    }
    if (b == 3 && t < 64) {
      float s = b_out[t];
      for (int h = 0; h < 64; ++h) s = fmaf(bn2[h], W_out[h * 64 + t], s);
      bno[t] = s;
    }
  } else {
    const int bid = b - 7, nb = gridDim.x - 7;
    const int tot8 = N * 8;
    for (int i = bid * 256 + t; i < tot8; i += nb * 256) {
      const f32x4 v = *reinterpret_cast<const f32x4*>(nf + (size_t)i * 4);
      uint2 o;
      o.x = pack2bf(v[0], v[1]);
      o.y = pack2bf(v[2], v[3]);
      *reinterpret_cast<uint2*>(nfb + (size_t)i * 4) = o;
    }
    const size_t tot = (size_t)N * 68;
    for (size_t i = (size_t)bid * 256 + t; i * 4 < tot; i += (size_t)nb * 256) {
      const size_t off = i * 4;
      if (off + 4 <= tot)
        *reinterpret_cast<float4*>(aggz + off) = make_float4(0.f, 0.f, 0.f, 0.f);
      else
        for (size_t q = off; q < tot; ++q) aggz[q] = 0.f;
    }
  }
}

// ---------------- k_gab (+ fused hist) ----------------
__global__ __launch_bounds__(256) void k_gab(
    const float* __restrict__ nf, const float* __restrict__ WA,
    const float* __restrict__ WB, unsigned short* __restrict__ gA,
    unsigned short* __restrict__ gB, const int* __restrict__ eidx,
    int* __restrict__ deg, int N, int E, int gabBlocks) {
  if ((int)blockIdx.x >= gabBlocks) {
    const int hb = blockIdx.x - gabBlocks;
    const int nhb = gridDim.x - gabBlocks;
    for (int e = hb * 256 + threadIdx.x; e < E; e += nhb * 256)
      atomicAdd(&deg[eidx[e]], 1);
    return;
  }
  __shared__ float Ws[2 * 2048];
  __shared__ float nfl[4][8][36];
  for (int i = threadIdx.x; i < 2048; i += 256) {
    Ws[i] = WA[i];
    Ws[2048 + i] = WB[i];
  }
  __syncthreads();
  const int w = threadIdx.x >> 6, lane = threadIdx.x & 63;
  const int NG = (N + 7) >> 3;
  for (int ng = blockIdx.x * 4 + w; ng < NG; ng += gabBlocks * 4) {
    const int base = ng * 8;
    {
      const int nl = lane >> 3, ch = lane & 7;
      int n = base + nl;
      if (n >= N) n = N - 1;
      const f32x4 v = *reinterpret_cast<const f32x4*>(nf + (size_t)n * 32 + ch * 4);
      *reinterpret_cast<f32x4*>(&nfl[w][nl][ch * 4]) = v;
    }
    float aa[8], ab[8];
#pragma unroll
    for (int i = 0; i < 8; ++i) { aa[i] = 0.f; ab[i] = 0.f; }
    for (int k4 = 0; k4 < 8; ++k4) {
      float w0[2][4];
#pragma unroll
      for (int q = 0; q < 4; ++q) {
        w0[0][q] = Ws[(k4 * 4 + q) * 64 + lane];
        w0[1][q] = Ws[2048 + (k4 * 4 + q) * 64 + lane];
      }
#pragma unroll
      for (int i = 0; i < 8; ++i) {
        const f32x4 x = *reinterpret_cast<const f32x4*>(&nfl[w][i][k4 * 4]);
#pragma unroll
        for (int q = 0; q < 4; ++q) {
          aa[i] = fmaf(x[q], w0[0][q], aa[i]);
          ab[i] = fmaf(x[q], w0[1][q], ab[i]);
        }
      }
    }
#pragma unroll
    for (int i = 0; i < 8; ++i) {
      const int n = base + i;
      if (n < N) {
        gA[(size_t)n * 64 + lane] = f2bf(aa[i]);
        gB[(size_t)n * 64 + lane] = f2bf(ab[i]);
      }
    }
  }
}

// ---------------- scan + scatter ----------------
__global__ __launch_bounds__(256) void k_scanA(const int* __restrict__ deg,
                                               int* __restrict__ excl,
                                               int* __restrict__ bsum, int N) {
  __shared__ int s[256];
  const int t = threadIdx.x;
  const int i = blockIdx.x * 256 + t;
  const int v = (i < N) ? deg[i] : 0;
  s[t] = v;
  __syncthreads();
#pragma unroll
  for (int off = 1; off < 256; off <<= 1) {
    int x = 0;
    if (t >= off) x = s[t - off];
    __syncthreads();
    s[t] += x;
    __syncthreads();
  }
  if (i < N) excl[i] = s[t] - v;
  if (t == 255) bsum[blockIdx.x] = s[255];
}

__global__ __launch_bounds__(256) void k_scanC(int* __restrict__ excl,
                                               const int* __restrict__ bsum,
                                               int N) {
  __shared__ int sh[256];
  const int t = threadIdx.x, b = blockIdx.x;
  int part = 0;
  for (int i = t; i < b; i += 256) part += bsum[i];
  sh[t] = part;
  __syncthreads();
#pragma unroll
  for (int off = 128; off; off >>= 1) {
    if (t < off) sh[t] += sh[t + off];
    __syncthreads();
  }
  const int add = sh[0];
  const int i = b * 256 + t;
  if (i < N) excl[i] += add;
}

__global__ __launch_bounds__(256) void k_scatter(
    const int* __restrict__ eidx, const float* __restrict__ co,
    int* __restrict__ rowNext, unsigned long long* __restrict__ srt8,
    f32x4* __restrict__ cdr, int E) {
  for (int e = blockIdx.x * 256 + threadIdx.x; e < E; e += gridDim.x * 256) {
    const int r = eidx[e];
    const int c = eidx[E + e];
    const int pos = atomicAdd(&rowNext[r], 1);
    srt8[pos] = (unsigned long long)r | ((unsigned long long)c << 18) |
                ((unsigned long long)e << 36);
    const float dx = co[(size_t)r * 3 + 0] - co[(size_t)c * 3 + 0];
    const float dy = co[(size_t)r * 3 + 1] - co[(size_t)c * 3 + 1];
    const float dz = co[(size_t)r * 3 + 2] - co[(size_t)c * 3 + 2];
    f32x4 c4;
    c4[0] = dx; c4[1] = dy; c4[2] = dz; c4[3] = dx * dx + dy * dy + dz * dz;
    cdr[pos] = c4;
  }
}

// ---------------- k_edge: 2 adjacent 16-edge groups / wave ---------------
#define XS 76
struct EdgeLds {
  unsigned short We2t[64 * XS];
  unsigned short Wc1t[64 * XS];
  unsigned short Bea[64 * 40];
  unsigned short x[4][2][16 * XS];  // [wave][slot]
  float cd[4][2][16 * 4];
  int idx[4][2][16];
};

__global__ __launch_bounds__(256, 3) void k_edge(
    const unsigned short* __restrict__ gA, const unsigned short* __restrict__ gB,
    const float* __restrict__ ea, const f32x4* __restrict__ cdr,
    const unsigned long long* __restrict__ srt8, const float* __restrict__ We1,
    const float* __restrict__ bSum, const float* __restrict__ be2,
    const float* __restrict__ We2, const float* __restrict__ bc1,
    const float* __restrict__ Wc1, const float* __restrict__ Wc2,
    const float* __restrict__ bc2, float* __restrict__ agg_m,
    float* __restrict__ agg_x, int E) {
  __shared__ EdgeLds S;
  const int tid = threadIdx.x;
  for (int i = tid; i < 4096; i += 256) {
    const int k = i >> 6, n = i & 63;
    S.We2t[n * XS + k] = f2bf(We2[k * 64 + n]);
    S.Wc1t[n * XS + k] = f2bf(Wc1[k * 64 + n]);
  }
  for (int i = tid; i < 2048; i += 256) {
    const int k = i >> 6, n = i & 63;
    const float v = (k < 16) ? We1[(129 + k) * 64 + n]
                             : ((k == 16) ? We1[128 * 64 + n] : 0.f);
    S.Bea[n * 40 + k] = f2bf(v);
  }
  __syncthreads();

  const int w = tid >> 6, lane = tid & 63;
  const int g = lane >> 4, t = lane & 15;
  const float bc2v = bc2[0];

  float bS_r[4], be2_r[4], bc1_r[4], wc2_r[4];
#pragma unroll
  for (int nt = 0; nt < 4; ++nt) {
    const int n = t + 16 * nt;
    bS_r[nt] = bSum[n];
    be2_r[nt] = be2[n];
    bc1_r[nt] = bc1[n];
    wc2_r[nt] = Wc2[n];
  }

  const int ngroups = (E + 15) >> 4;
  const int GS2 = gridDim.x * 8;  // 4 waves x 2 groups per block

  for (int gp = blockIdx.x * 8 + w * 2; gp < ngroups; gp += GS2) {
    int e0p[2];
    int rD[2], cD[2], pD[2];
    // ---- decode + cdr (both slots) ----
#pragma unroll
    for (int p = 0; p < 2; ++p) {
      e0p[p] = (gp + p) * 16;
      unsigned long long s8 = 0;
      if (lane < 16) {
        long e = (long)e0p[p] + lane;
        if (e >= E) e = E - 1;
        s8 = srt8[e];
        *reinterpret_cast<f32x4*>(&S.cd[w][p][lane * 4]) = cdr[e];
      }
      rD[p] = (int)(s8 & 0x3FFFFull);
      cD[p] = (int)((s8 >> 18) & 0x3FFFFull);
      pD[p] = (int)(s8 >> 36);
      if (lane < 16) S.idx[w][p][lane] = rD[p];
    }
    // ---- staging (both slots) ----
#pragma unroll
    for (int p = 0; p < 2; ++p) {
      unsigned short* xw = &S.x[w][p][0];
#pragma unroll
      for (int rr = 0; rr < 2; ++rr) {
        const int el = rr * 8 + (lane >> 3), ch = lane & 7;
        const int rI = __shfl(rD[p], el, 64);
        const int cI = __shfl(cD[p], el, 64);
        const uint4 va = *reinterpret_cast<const uint4*>(gA + (size_t)rI * 64 + ch * 8);
        const uint4 vb = *reinterpret_cast<const uint4*>(gB + (size_t)cI * 64 + ch * 8);
        const unsigned int a[4] = {va.x, va.y, va.z, va.w};
        const unsigned int b[4] = {vb.x, vb.y, vb.z, vb.w};
        uint4 o;
        unsigned int r[4];
#pragma unroll
        for (int q = 0; q < 4; ++q) {
          const float s0 = lo_bf(a[q]) + lo_bf(b[q]);
          const float s1 = hi_bf(a[q]) + hi_bf(b[q]);
          r[q] = pack2bf(s0, s1);
        }
        o.x = r[0]; o.y = r[1]; o.z = r[2]; o.w = r[3];
        *reinterpret_cast<uint4*>(&xw[el * XS + ch * 8]) = o;
      }
    }
    // ---- layer-1 A fragments (both) ----
    short8 a1[2];
#pragma unroll
    for (int p = 0; p < 2; ++p) {
      const int eaI = __shfl(pD[p], t, 64);
      short8 a = {};
      if (g < 2) {
        const float* pe2 = ea + (size_t)eaI * 16 + g * 8;
        const f32x4 x0 = *reinterpret_cast<const f32x4*>(pe2);
        const f32x4 x1 = *reinterpret_cast<const f32x4*>(pe2 + 4);
        const unsigned int p0 = pack2bf(x0[0], x0[1]);
        const unsigned int p1 = pack2bf(x0[2], x0[3]);
        const unsigned int p2 = pack2bf(x1[0], x1[1]);
        const unsigned int p3 = pack2bf(x1[2], x1[3]);
        a[0] = (short)(p0 & 0xFFFF); a[1] = (short)(p0 >> 16);
        a[2] = (short)(p1 & 0xFFFF); a[3] = (short)(p1 >> 16);
        a[4] = (short)(p2 & 0xFFFF); a[5] = (short)(p2 >> 16);
        a[6] = (short)(p3 & 0xFFFF); a[7] = (short)(p3 >> 16);
      } else if (g == 2) {
        a[0] = (short)f2bf(S.cd[w][p][t * 4 + 3]);
      }
      a1[p] = a;
    }
    // ---- layer 1: C-init + MFMA + t1 store (both) ----
    f32x4 acc[2][4];
#pragma unroll
    for (int p = 0; p < 2; ++p) {
      unsigned short* xw = &S.x[w][p][0];
#pragma unroll
      for (int nt = 0; nt < 4; ++nt)
#pragma unroll
        for (int j = 0; j < 4; ++j)
          acc[p][nt][j] = bf2f(xw[(g * 4 + j) * XS + t + 16 * nt]) + bS_r[nt];
    }
#pragma unroll
    for (int p = 0; p < 2; ++p)
#pragma unroll
      for (int nt = 0; nt < 4; ++nt) {
        const short8 b = *reinterpret_cast<const short8*>(&S.Bea[(t + 16 * nt) * 40 + g * 8]);
        acc[p][nt] = __builtin_amdgcn_mfma_f32_16x16x32_bf16(a1[p], b, acc[p][nt], 0, 0, 0);
      }
#pragma unroll
    for (int p = 0; p < 2; ++p) {
      unsigned short* xw = &S.x[w][p][0];
#pragma unroll
      for (int nt = 0; nt < 4; ++nt) {
        const unsigned int pk01 = pack2bf(fmaxf(acc[p][nt][0], 0.f), fmaxf(acc[p][nt][1], 0.f));
        const unsigned int pk23 = pack2bf(fmaxf(acc[p][nt][2], 0.f), fmaxf(acc[p][nt][3], 0.f));
        xw[(g * 4 + 0) * XS + t + 16 * nt] = (unsigned short)(pk01 & 0xFFFF);
        xw[(g * 4 + 1) * XS + t + 16 * nt] = (unsigned short)(pk01 >> 16);
        xw[(g * 4 + 2) * XS + t + 16 * nt] = (unsigned short)(pk23 & 0xFFFF);
        xw[(g * 4 + 3) * XS + t + 16 * nt] = (unsigned short)(pk23 >> 16);
      }
    }
    // ---- layer 2 (both): m = relu(t1 @ We2 + be2) ----
#pragma unroll
    for (int p = 0; p < 2; ++p) {
      unsigned short* xw = &S.x[w][p][0];
      short8 A2[2];
#pragma unroll
      for (int kt = 0; kt < 2; ++kt)
        A2[kt] = *reinterpret_cast<const short8*>(&xw[t * XS + kt * 32 + g * 8]);
#pragma unroll
      for (int nt = 0; nt < 4; ++nt) {
        f32x4 c;
        c[0] = be2_r[nt]; c[1] = be2_r[nt]; c[2] = be2_r[nt]; c[3] = be2_r[nt];
#pragma unroll
        for (int kt = 0; kt < 2; ++kt) {
          const short8 b = *reinterpret_cast<const short8*>(
              &S.We2t[(t + 16 * nt) * XS + kt * 32 + g * 8]);
          c = __builtin_amdgcn_mfma_f32_16x16x32_bf16(A2[kt], b, c, 0, 0, 0);
        }
#pragma unroll
        for (int j = 0; j < 4; ++j) c[j] = fmaxf(c[j], 0.f);
        acc[p][nt] = c;  // reuse acc as m2
      }
    }
#pragma unroll
    for (int p = 0; p < 2; ++p) {
      unsigned short* xw = &S.x[w][p][0];
#pragma unroll
      for (int nt = 0; nt < 4; ++nt) {
        const unsigned int pk01 = pack2bf(acc[p][nt][0], acc[p][nt][1]);
        const unsigned int pk23 = pack2bf(acc[p][nt][2], acc[p][nt][3]);
        xw[(g * 4 + 0) * XS + t + 16 * nt] = (unsigned short)(pk01 & 0xFFFF);
        xw[(g * 4 + 1) * XS + t + 16 * nt] = (unsigned short)(pk01 >> 16);
        xw[(g * 4 + 2) * XS + t + 16 * nt] = (unsigned short)(pk23 & 0xFFFF);
        xw[(g * 4 + 3) * XS + t + 16 * nt] = (unsigned short)(pk23 >> 16);
      }
    }
    // ---- coord MLP + s reduce (both) ----
#pragma unroll
    for (int p = 0; p < 2; ++p) {
      unsigned short* xw = &S.x[w][p][0];
      short8 A3[2];
#pragma unroll
      for (int kt = 0; kt < 2; ++kt)
        A3[kt] = *reinterpret_cast<const short8*>(&xw[t * XS + kt * 32 + g * 8]);
      float sv[4];
#pragma unroll
      for (int j = 0; j < 4; ++j) sv[j] = 0.f;
#pragma unroll
      for (int nt = 0; nt < 4; ++nt) {
        f32x4 c;
        c[0] = bc1_r[nt]; c[1] = bc1_r[nt]; c[2] = bc1_r[nt]; c[3] = bc1_r[nt];
#pragma unroll
        for (int kt = 0; kt < 2; ++kt) {
          const short8 b = *reinterpret_cast<const short8*>(
              &S.Wc1t[(t + 16 * nt) * XS + kt * 32 + g * 8]);
          c = __builtin_amdgcn_mfma_f32_16x16x32_bf16(A3[kt], b, c, 0, 0, 0);
        }
#pragma unroll
        for (int j = 0; j < 4; ++j) sv[j] = fmaf(fmaxf(c[j], 0.f), wc2_r[nt], sv[j]);
      }
#pragma unroll
      for (int d = 1; d < 16; d <<= 1)
#pragma unroll
        for (int j = 0; j < 4; ++j) sv[j] += __shfl_xor(sv[j], d, 64);
#pragma unroll
      for (int j = 0; j < 4; ++j) sv[j] += bc2v;
#pragma unroll
      for (int j = 0; j < 4; ++j)
        if (t == 0) S.cd[w][p][(g * 4 + j) * 4 + 3] = sv[j];
    }
    // ---- run-compressed agg_m (both) ----
#pragma unroll
    for (int p = 0; p < 2; ++p) {
      unsigned short* xw = &S.x[w][p][0];
      int* idxw = &S.idx[w][p][0];
      const int e0 = e0p[p];
      float accm = 0.f;
#pragma unroll
      for (int r = 0; r < 16; ++r) {
        const int rIr = idxw[r];
        const bool valid = (e0 + r) < E;
        if (valid) accm += bf2f(xw[r * XS + lane]);
        const bool closes = (r == 15) || ((e0 + r + 1) >= E) || (idxw[r + 1] != rIr);
        if (valid && closes) {
          atomAddF(&agg_m[(size_t)rIr * 64 + lane], accm);
          accm = 0.f;
        }
      }
    }
    // ---- run-compressed agg_x (both; lanes 0..2) ----
#pragma unroll
    for (int p = 0; p < 2; ++p) {
      if (lane < 3) {
        int* idxw = &S.idx[w][p][0];
        float* cdw = &S.cd[w][p][0];
        const int e0 = e0p[p];
        float accx = 0.f;
#pragma unroll
        for (int r = 0; r < 16; ++r) {
          const int rIr = idxw[r];
          const bool valid = (e0 + r) < E;
          if (valid) accx += cdw[r * 4 + lane] * cdw[r * 4 + 3];
          const bool closes = (r == 15) || ((e0 + r + 1) >= E) || (idxw[r + 1] != rIr);
          if (valid && closes) {
            atomAddF(&agg_x[(size_t)rIr * 3 + lane], accx);
            accx = 0.f;
          }
        }
      }
    }
  }
}
#undef XS

// ---------------- k_node (MFMA, folded weights) ----------------
struct NodeLds {
  unsigned short Wn1bT[64 * 72];
  unsigned short WnoT[64 * 72];
  unsigned short x[4][32 * 72];
};

__global__ __launch_bounds__(256, 4) void k_node(
    const unsigned short* __restrict__ nfb, const float* __restrict__ agg_m,
    const float* __restrict__ agg_x, const int* __restrict__ deg,
    const float* __restrict__ co, const float* __restrict__ WF1,
    const float* __restrict__ Wn1, const float* __restrict__ Wno,
    const float* __restrict__ bn1f, const float* __restrict__ bno,
    float* __restrict__ out, float* __restrict__ co_out, int N) {
  __shared__ NodeLds S;
  const int tid = threadIdx.x;
  for (int i = tid; i < 4096; i += 256) {
    const int k = i >> 6, n = i & 63;
    S.Wn1bT[n * 72 + k] = f2bf(Wn1[(64 + k) * 64 + n]);
    S.WnoT[n * 72 + k] = f2bf(Wno[k * 64 + n]);
  }
  __syncthreads();
  const int w = tid >> 6, lane = tid & 63;
  const int g = lane >> 4, t = lane & 15;

  short8 fW1[4];
  float b1_r[4], bo_r[4];
#pragma unroll
  for (int nt = 0; nt < 4; ++nt) {
    const int n = t + 16 * nt;
    short8 a;
#pragma unroll
    for (int j = 0; j < 8; ++j) a[j] = (short)f2bf(WF1[(g * 8 + j) * 64 + n]);
    fW1[nt] = a;
    b1_r[nt] = bn1f[n];
    bo_r[nt] = bno[n];
  }

  unsigned short* xw = &S.x[w][0];
  const int ngroups = (N + 31) >> 5;
  const int GS = gridDim.x * 4;

  for (int grp = blockIdx.x * 4 + w; grp < ngroups; grp += GS) {
    const int base = grp * 32;
    short8 A1[2], Aa[2][2];
#pragma unroll
    for (int mt = 0; mt < 2; ++mt) {
      int node = base + t + 16 * mt;
      if (node >= N) node = N - 1;
      A1[mt] = *reinterpret_cast<const short8*>(nfb + (size_t)node * 32 + g * 8);
#pragma unroll
      for (int kt = 0; kt < 2; ++kt) {
        const f32x4 v0 = *reinterpret_cast<const f32x4*>(
            agg_m + (size_t)node * 64 + kt * 32 + g * 8);
        const f32x4 v1 = *reinterpret_cast<const f32x4*>(
            agg_m + (size_t)node * 64 + kt * 32 + g * 8 + 4);
        const unsigned int p0 = pack2bf(v0[0], v0[1]);
        const unsigned int p1 = pack2bf(v0[2], v0[3]);
        const unsigned int p2 = pack2bf(v1[0], v1[1]);
        const unsigned int p3 = pack2bf(v1[2], v1[3]);
        short8 a;
        a[0] = (short)(p0 & 0xFFFF); a[1] = (short)(p0 >> 16);
        a[2] = (short)(p1 & 0xFFFF); a[3] = (short)(p1 >> 16);
        a[4] = (short)(p2 & 0xFFFF); a[5] = (short)(p2 >> 16);
        a[6] = (short)(p3 & 0xFFFF); a[7] = (short)(p3 >> 16);
        Aa[mt][kt] = a;
      }
    }
    f32x4 acc[2][4];
#pragma unroll
    for (int mt = 0; mt < 2; ++mt)
#pragma unroll
      for (int nt = 0; nt < 4; ++nt) {
        const int n = t + 16 * nt;
        f32x4 c;
        c[0] = b1_r[nt]; c[1] = b1_r[nt]; c[2] = b1_r[nt]; c[3] = b1_r[nt];
        c = __builtin_amdgcn_mfma_f32_16x16x32_bf16(A1[mt], fW1[nt], c, 0, 0, 0);
#pragma unroll
        for (int kt = 0; kt < 2; ++kt) {
          const short8 b = *reinterpret_cast<const short8*>(
              &S.Wn1bT[n * 72 + kt * 32 + g * 8]);
          c = __builtin_amdgcn_mfma_f32_16x16x32_bf16(Aa[mt][kt], b, c, 0, 0, 0);
        }
        acc[mt][nt] = c;
      }
#pragma unroll
    for (int mt = 0; mt < 2; ++mt)
#pragma unroll
      for (int nt = 0; nt < 4; ++nt)
#pragma unroll
        for (int j = 0; j < 4; ++j)
          xw[(g * 4 + j + 16 * mt) * 72 + t + 16 * nt] =
              f2bf(fmaxf(acc[mt][nt][j], 0.f));
    short8 A2[2][2];
#pragma unroll
    for (int mt = 0; mt < 2; ++mt)
#pragma unroll
      for (int kt = 0; kt < 2; ++kt)
        A2[mt][kt] = *reinterpret_cast<const short8*>(
            &S.x[w][(t + 16 * mt) * 72 + kt * 32 + g * 8]);
#pragma unroll
    for (int mt = 0; mt < 2; ++mt)
#pragma unroll
      for (int nt = 0; nt < 4; ++nt) {
        const int n = t + 16 * nt;
        f32x4 c;
        c[0] = bo_r[nt]; c[1] = bo_r[nt]; c[2] = bo_r[nt]; c[3] = bo_r[nt];
#pragma unroll
        for (int kt = 0; kt < 2; ++kt) {
          const short8 b = *reinterpret_cast<const short8*>(
              &S.WnoT[n * 72 + kt * 32 + g * 8]);
          c = __builtin_amdgcn_mfma_f32_16x16x32_bf16(A2[mt][kt], b, c, 0, 0, 0);
        }
#pragma unroll
        for (int j = 0; j < 4; ++j) {
          const int node = base + g * 4 + j + 16 * mt;
          if (node < N) out[(size_t)node * 64 + n] = c[j];
        }
      }
    if (lane < 32) {
      const int node = base + lane;
      if (node < N) {
        const float dv = fmaxf((float)deg[node], 1.f);
#pragma unroll
        for (int d = 0; d < 3; ++d)
          co_out[(size_t)node * 3 + d] =
              co[(size_t)node * 3 + d] + agg_x[(size_t)node * 3 + d] / dv;
      }
    }
  }
}

extern "C" void kernel_launch(void* const* d_in, const int* in_sizes, int n_in,
                              void* d_out, int out_size, void* d_ws, size_t ws_size,
                              hipStream_t stream) {
  const float* nf = (const float*)d_in[0];
  const float* ea = (const float*)d_in[1];
  const float* co = (const float*)d_in[2];
  const int* ei = (const int*)d_in[3];
  const float* W_in = (const float*)d_in[4];
  const float* b_in = (const float*)d_in[5];
  const float* W_out = (const float*)d_in[6];
  const float* b_out = (const float*)d_in[7];
  const float* We1 = (const float*)d_in[8];
  const float* be1 = (const float*)d_in[9];
  const float* We2 = (const float*)d_in[10];
  const float* be2 = (const float*)d_in[11];
  const float* Wn1 = (const float*)d_in[12];
  const float* bn1 = (const float*)d_in[13];
  const float* Wn2 = (const float*)d_in[14];
  const float* bn2 = (const float*)d_in[15];
  const float* Wc1 = (const float*)d_in[16];
  const float* bc1 = (const float*)d_in[17];
  const float* Wc2 = (const float*)d_in[18];
  const float* bc2 = (const float*)d_in[19];

  const int N = in_sizes[0] / 32;
  const int E = in_sizes[1] / 16;

  float* ws = (float*)d_ws;
  float* agg_m = ws;                                   // N*64
  float* agg_x = agg_m + (size_t)N * 64;               // N*3
  int* deg = (int*)(agg_x + (size_t)N * 3);            // N
  float* WA = (float*)(deg + N);                       // 2048
  float* WB = WA + 2048;
  float* WF1 = WB + 2048;
  float* Wno = WF1 + 2048;                             // 4096
  float* bSum = Wno + 4096;                            // 64
  float* bn1f = bSum + 64;
  float* bno = bn1f + 64;
  int* rowNext = (int*)(bno + 64);                     // N
  int* bsumBuf = rowNext + N;                          // 512
  uintptr_t pp = (uintptr_t)(bsumBuf + 512);
  pp = (pp + 15) & ~(uintptr_t)15;
  f32x4* cdr = (f32x4*)pp;                             // E (16B aligned)
  unsigned long long* srt8 = (unsigned long long*)(cdr + E);  // E
  unsigned short* nfb = (unsigned short*)(srt8 + E);   // N*32

  float* outp = (float*)d_out;
  float* co_out = outp + (size_t)N * 64;
  unsigned short* gA = (unsigned short*)d_out;         // N*64 bf16 (scratch)
  unsigned short* gB = gA + (size_t)N * 64;            // N*64 bf16

  const int nb = (N + 255) / 256;

  k_prep<<<1031, 256, 0, stream>>>(nf, W_in, b_in, We1, be1, Wn1, bn1, Wn2,
                                   bn2, W_out, b_out, nfb, WA, WB, WF1, Wno,
                                   bSum, bn1f, bno, agg_m, N);
  k_gab<<<2048 + 512, 256, 0, stream>>>(nf, WA, WB, gA, gB, ei, deg, N, E, 2048);
  k_scanA<<<nb, 256, 0, stream>>>(deg, rowNext, bsumBuf, N);
  k_scanC<<<nb, 256, 0, stream>>>(rowNext, bsumBuf, N);
  k_scatter<<<1024, 256, 0, stream>>>(ei, co, rowNext, srt8, cdr, E);
  k_edge<<<1024, 256, 0, stream>>>(gA, gB, ea, cdr, srt8, We1, bSum, be2, We2,
                                   bc1, Wc1, Wc2, bc2, agg_m, agg_x, E);
  k_node<<<1024, 256, 0, stream>>>(nfb, agg_m, agg_x, deg, co, WF1, Wn1, Wno,
                                   bn1f, bno, outp, co_out, N);
}

// Round 20
// 383.336 us; speedup vs baseline: 1.1672x; 1.1672x over previous
//
#include <hip/hip_runtime.h>
#include <hip/hip_bf16.h>

// EGNN forward — REVERT to r18 (best stable config, ~392µs total).
// r19's 2-group ILP regressed (occ 42->25.5%, VGPR 60->76, k_edge +40%) —
// fifth failed latency/ILP attempt on k_edge; its ~217µs is a structural
// plateau for this decomposition (no pipe >40%, all levers null/negative).
// Pipeline: k_prep -> k_gab(+hist) -> k_scanA -> k_scanC -> k_scatter(+cdr)
//   -> k_edge -> k_node.
// ws: agg_m[N*64]f | agg_x[N*3]f | deg[N]i | WA[2048]f | WB[2048]f | WF1[2048]f
//   | Wno[4096]f | bSum[64]f | bn1f[64]f | bno[64]f | rowNext[N]i | bsumBuf[512]i
//   | cdr[E]f32x4 | srt8[E]u64 | nfb[N*32]bf16
// d_out: out[N*64] | coords_out[N*3]; doubles as bf16 gA/gB scratch.
//
// Locked: (r3) shfl in uniform flow; (r6,r10) no bounds(,4)/persistent frags;
// (r13) weights in LDS; (r14) 16-edge tile; (r16) cvt_pk; (r17) cdr precompute;
// (r18) stride-76 pad; (r4,r8,r12,r19) NO register pipelines / multi-group ILP.

typedef __attribute__((ext_vector_type(4))) float f32x4;
typedef __attribute__((ext_vector_type(8))) short short8;

__device__ __forceinline__ void atomAddF(float* p, float v) { unsafeAtomicAdd(p, v); }

__device__ __forceinline__ unsigned int pack2bf(float lo, float hi) {
  unsigned int r;
  asm("v_cvt_pk_bf16_f32 %0, %1, %2" : "=v"(r) : "v"(lo), "v"(hi));
  return r;  // lo -> bits [15:0], hi -> bits [31:16]
}
__device__ __forceinline__ unsigned short f2bf(float f) {
  return (unsigned short)(pack2bf(f, 0.f) & 0xFFFFu);
}
__device__ __forceinline__ float bf2f(unsigned short s) {
  unsigned int v = ((unsigned int)s) << 16;
  return __builtin_bit_cast(float, v);
}
__device__ __forceinline__ float lo_bf(unsigned int u) {
  return __builtin_bit_cast(float, u << 16);
}
__device__ __forceinline__ float hi_bf(unsigned int u) {
  return __builtin_bit_cast(float, u & 0xFFFF0000u);
}

// ---------------- k_prep: folds + nf->bf16 + agg/deg zero ----------------
__global__ __launch_bounds__(256) void k_prep(
    const float* __restrict__ nf, const float* __restrict__ W_in,
    const float* __restrict__ b_in, const float* __restrict__ We1,
    const float* __restrict__ be1, const float* __restrict__ Wn1,
    const float* __restrict__ bn1, const float* __restrict__ Wn2,
    const float* __restrict__ bn2, const float* __restrict__ W_out,
    const float* __restrict__ b_out, unsigned short* __restrict__ nfb,
    float* __restrict__ WA, float* __restrict__ WB, float* __restrict__ WF1,
    float* __restrict__ Wno, float* __restrict__ bSum, float* __restrict__ bn1f,
    float* __restrict__ bno, float* __restrict__ aggz, int N) {
  const int b = blockIdx.x, t = threadIdx.x;
  if (b == 0 || b == 1) {
    const float* Wsrc = (b == 0) ? We1 : (We1 + 64 * 64);
    float* dst = (b == 0) ? WA : WB;
    for (int idx = t; idx < 2048; idx += 256) {
      const int i = idx >> 6, n = idx & 63;
      float s = 0.f;
      for (int h = 0; h < 64; ++h) s = fmaf(W_in[i * 64 + h], Wsrc[h * 64 + n], s);
      dst[idx] = s;
    }
  } else if (b == 2) {
    for (int idx = t; idx < 2048; idx += 256) {
      const int i = idx >> 6, n = idx & 63;
      float s = 0.f;
      for (int h = 0; h < 64; ++h) s = fmaf(W_in[i * 64 + h], Wn1[h * 64 + n], s);
      WF1[idx] = s;
    }
    if (t < 64) {
      float s1 = bn1[t], s2 = be1[t];
      for (int h = 0; h < 64; ++h) {
        s1 = fmaf(b_in[h], Wn1[h * 64 + t], s1);
        s2 = fmaf(b_in[h], We1[h * 64 + t] + We1[(64 + h) * 64 + t], s2);
      }
      bn1f[t] = s1;
      bSum[t] = s2;
    }
  } else if (b <= 6) {
    const int base = (b - 3) * 1024;
    for (int idx = t; idx < 1024; idx += 256) {
      const int kk = (base + idx) >> 6, n = (base + idx) & 63;
      float s = 0.f;
      for (int h = 0; h < 64; ++h) s = fmaf(Wn2[kk * 64 + h], W_out[h * 64 + n], s);
      Wno[base + idx] = s;
    }
    if (b == 3 && t < 64) {
      float s = b_out[t];
      for (int h = 0; h < 64; ++h) s = fmaf(bn2[h], W_out[h * 64 + t], s);
      bno[t] = s;
    }
  } else {
    const int bid = b - 7, nb = gridDim.x - 7;
    const int tot8 = N * 8;
    for (int i = bid * 256 + t; i < tot8; i += nb * 256) {
      const f32x4 v = *reinterpret_cast<const f32x4*>(nf + (size_t)i * 4);
      uint2 o;
      o.x = pack2bf(v[0], v[1]);
      o.y = pack2bf(v[2], v[3]);
      *reinterpret_cast<uint2*>(nfb + (size_t)i * 4) = o;
    }
    const size_t tot = (size_t)N * 68;  // agg_m | agg_x | deg (all zeroed)
    for (size_t i = (size_t)bid * 256 + t; i * 4 < tot; i += (size_t)nb * 256) {
      const size_t off = i * 4;
      if (off + 4 <= tot)
        *reinterpret_cast<float4*>(aggz + off) = make_float4(0.f, 0.f, 0.f, 0.f);
      else
        for (size_t q = off; q < tot; ++q) aggz[q] = 0.f;
    }
  }
}

// ---------------- k_gab (+ fused hist; deg zeroed by k_prep) -------------
__global__ __launch_bounds__(256) void k_gab(
    const float* __restrict__ nf, const float* __restrict__ WA,
    const float* __restrict__ WB, unsigned short* __restrict__ gA,
    unsigned short* __restrict__ gB, const int* __restrict__ eidx,
    int* __restrict__ deg, int N, int E, int gabBlocks) {
  if ((int)blockIdx.x >= gabBlocks) {
    const int hb = blockIdx.x - gabBlocks;
    const int nhb = gridDim.x - gabBlocks;
    for (int e = hb * 256 + threadIdx.x; e < E; e += nhb * 256)
      atomicAdd(&deg[eidx[e]], 1);
    return;
  }
  __shared__ float Ws[2 * 2048];
  __shared__ float nfl[4][8][36];
  for (int i = threadIdx.x; i < 2048; i += 256) {
    Ws[i] = WA[i];
    Ws[2048 + i] = WB[i];
  }
  __syncthreads();
  const int w = threadIdx.x >> 6, lane = threadIdx.x & 63;
  const int NG = (N + 7) >> 3;
  for (int ng = blockIdx.x * 4 + w; ng < NG; ng += gabBlocks * 4) {
    const int base = ng * 8;
    {
      const int nl = lane >> 3, ch = lane & 7;
      int n = base + nl;
      if (n >= N) n = N - 1;
      const f32x4 v = *reinterpret_cast<const f32x4*>(nf + (size_t)n * 32 + ch * 4);
      *reinterpret_cast<f32x4*>(&nfl[w][nl][ch * 4]) = v;
    }
    float aa[8], ab[8];
#pragma unroll
    for (int i = 0; i < 8; ++i) { aa[i] = 0.f; ab[i] = 0.f; }
    for (int k4 = 0; k4 < 8; ++k4) {
      float w0[2][4];
#pragma unroll
      for (int q = 0; q < 4; ++q) {
        w0[0][q] = Ws[(k4 * 4 + q) * 64 + lane];
        w0[1][q] = Ws[2048 + (k4 * 4 + q) * 64 + lane];
      }
#pragma unroll
      for (int i = 0; i < 8; ++i) {
        const f32x4 x = *reinterpret_cast<const f32x4*>(&nfl[w][i][k4 * 4]);
#pragma unroll
        for (int q = 0; q < 4; ++q) {
          aa[i] = fmaf(x[q], w0[0][q], aa[i]);
          ab[i] = fmaf(x[q], w0[1][q], ab[i]);
        }
      }
    }
#pragma unroll
    for (int i = 0; i < 8; ++i) {
      const int n = base + i;
      if (n < N) {
        gA[(size_t)n * 64 + lane] = f2bf(aa[i]);
        gB[(size_t)n * 64 + lane] = f2bf(ab[i]);
      }
    }
  }
}

// ---------------- scan + scatter ----------------
__global__ __launch_bounds__(256) void k_scanA(const int* __restrict__ deg,
                                               int* __restrict__ excl,
                                               int* __restrict__ bsum, int N) {
  __shared__ int s[256];
  const int t = threadIdx.x;
  const int i = blockIdx.x * 256 + t;
  const int v = (i < N) ? deg[i] : 0;
  s[t] = v;
  __syncthreads();
#pragma unroll
  for (int off = 1; off < 256; off <<= 1) {
    int x = 0;
    if (t >= off) x = s[t - off];
    __syncthreads();
    s[t] += x;
    __syncthreads();
  }
  if (i < N) excl[i] = s[t] - v;
  if (t == 255) bsum[blockIdx.x] = s[255];
}

__global__ __launch_bounds__(256) void k_scanC(int* __restrict__ excl,
                                               const int* __restrict__ bsum,
                                               int N) {
  __shared__ int sh[256];
  const int t = threadIdx.x, b = blockIdx.x;
  int part = 0;
  for (int i = t; i < b; i += 256) part += bsum[i];
  sh[t] = part;
  __syncthreads();
#pragma unroll
  for (int off = 128; off; off >>= 1) {
    if (t < off) sh[t] += sh[t + off];
    __syncthreads();
  }
  const int add = sh[0];
  const int i = b * 256 + t;
  if (i < N) excl[i] += add;
}

__global__ __launch_bounds__(256) void k_scatter(
    const int* __restrict__ eidx, const float* __restrict__ co,
    int* __restrict__ rowNext, unsigned long long* __restrict__ srt8,
    f32x4* __restrict__ cdr, int E) {
  for (int e = blockIdx.x * 256 + threadIdx.x; e < E; e += gridDim.x * 256) {
    const int r = eidx[e];
    const int c = eidx[E + e];
    const int pos = atomicAdd(&rowNext[r], 1);
    srt8[pos] = (unsigned long long)r | ((unsigned long long)c << 18) |
                ((unsigned long long)e << 36);
    const float dx = co[(size_t)r * 3 + 0] - co[(size_t)c * 3 + 0];
    const float dy = co[(size_t)r * 3 + 1] - co[(size_t)c * 3 + 1];
    const float dz = co[(size_t)r * 3 + 2] - co[(size_t)c * 3 + 2];
    f32x4 c4;
    c4[0] = dx; c4[1] = dy; c4[2] = dz; c4[3] = dx * dx + dy * dy + dz * dz;
    cdr[pos] = c4;
  }
}

// ---------------- k_edge (16-edge groups; stride-76 LDS, ~35.6KB) --------
#define XS 76  // padded stride (shorts): 38 dwords -> g-groups hit disjoint banks
struct EdgeLds {
  unsigned short We2t[64 * XS];
  unsigned short Wc1t[64 * XS];
  unsigned short Bea[64 * 40];
  unsigned short x[4][16 * XS];  // staged sum -> t1 -> m (bf16)
  float cd[4][16 * 4];           // dx,dy,dz,(radial -> s)
  int idx[4][16];                // sorted row ids
};

__global__ __launch_bounds__(256, 3) void k_edge(
    const unsigned short* __restrict__ gA, const unsigned short* __restrict__ gB,
    const float* __restrict__ ea, const f32x4* __restrict__ cdr,
    const unsigned long long* __restrict__ srt8, const float* __restrict__ We1,
    const float* __restrict__ bSum, const float* __restrict__ be2,
    const float* __restrict__ We2, const float* __restrict__ bc1,
    const float* __restrict__ Wc1, const float* __restrict__ Wc2,
    const float* __restrict__ bc2, float* __restrict__ agg_m,
    float* __restrict__ agg_x, int E) {
  __shared__ EdgeLds S;
  const int tid = threadIdx.x;
  for (int i = tid; i < 4096; i += 256) {
    const int k = i >> 6, n = i & 63;
    S.We2t[n * XS + k] = f2bf(We2[k * 64 + n]);
    S.Wc1t[n * XS + k] = f2bf(Wc1[k * 64 + n]);
  }
  for (int i = tid; i < 2048; i += 256) {
    const int k = i >> 6, n = i & 63;
    const float v = (k < 16) ? We1[(129 + k) * 64 + n]
                             : ((k == 16) ? We1[128 * 64 + n] : 0.f);
    S.Bea[n * 40 + k] = f2bf(v);
  }
  __syncthreads();

  const int w = tid >> 6, lane = tid & 63;
  const int g = lane >> 4, t = lane & 15;
  const float bc2v = bc2[0];

  float bS_r[4], be2_r[4], bc1_r[4], wc2_r[4];
#pragma unroll
  for (int nt = 0; nt < 4; ++nt) {
    const int n = t + 16 * nt;
    bS_r[nt] = bSum[n];
    be2_r[nt] = be2[n];
    bc1_r[nt] = bc1[n];
    wc2_r[nt] = Wc2[n];
  }

  unsigned short* xw = &S.x[w][0];
  float* cdw = &S.cd[w][0];
  int* idxw = &S.idx[w][0];
  const int ngroups = (E + 15) >> 4;
  const int GS = gridDim.x * 4;

  for (int grp = blockIdx.x * 4 + w; grp < ngroups; grp += GS) {
    const int e0 = grp * 16;
    unsigned long long s8 = 0;
    if (lane < 16) {
      int e = e0 + lane;
      if (e >= E) e = E - 1;
      s8 = srt8[e];
      *reinterpret_cast<f32x4*>(&cdw[lane * 4]) = cdr[e];
    }
    const int r_dec = (int)(s8 & 0x3FFFFull);
    const int c_dec = (int)((s8 >> 18) & 0x3FFFFull);
    const int p_dec = (int)(s8 >> 36);
    if (lane < 16) idxw[lane] = r_dec;

    // --- gA[row]+gB[col] staged sum -> x tile ---
#pragma unroll
    for (int rr = 0; rr < 2; ++rr) {
      const int el = rr * 8 + (lane >> 3), ch = lane & 7;
      const int rI = __shfl(r_dec, el, 64);
      const int cI = __shfl(c_dec, el, 64);
      const uint4 va = *reinterpret_cast<const uint4*>(gA + (size_t)rI * 64 + ch * 8);
      const uint4 vb = *reinterpret_cast<const uint4*>(gB + (size_t)cI * 64 + ch * 8);
      const unsigned int a[4] = {va.x, va.y, va.z, va.w};
      const unsigned int b[4] = {vb.x, vb.y, vb.z, vb.w};
      uint4 o;
      unsigned int r[4];
#pragma unroll
      for (int q = 0; q < 4; ++q) {
        const float s0 = lo_bf(a[q]) + lo_bf(b[q]);
        const float s1 = hi_bf(a[q]) + hi_bf(b[q]);
        r[q] = pack2bf(s0, s1);
      }
      o.x = r[0]; o.y = r[1]; o.z = r[2]; o.w = r[3];
      *reinterpret_cast<uint4*>(&xw[el * XS + ch * 8]) = o;
    }

    // --- layer-1 A fragment: ea (via perm) + radial ---
    short8 a1;
    {
      const int eaI = __shfl(p_dec, t, 64);
      short8 a = {};
      if (g < 2) {
        const float* pe2 = ea + (size_t)eaI * 16 + g * 8;
        const f32x4 x0 = *reinterpret_cast<const f32x4*>(pe2);
        const f32x4 x1 = *reinterpret_cast<const f32x4*>(pe2 + 4);
        const unsigned int p0 = pack2bf(x0[0], x0[1]);
        const unsigned int p1 = pack2bf(x0[2], x0[3]);
        const unsigned int p2 = pack2bf(x1[0], x1[1]);
        const unsigned int p3 = pack2bf(x1[2], x1[3]);
        a[0] = (short)(p0 & 0xFFFF); a[1] = (short)(p0 >> 16);
        a[2] = (short)(p1 & 0xFFFF); a[3] = (short)(p1 >> 16);
        a[4] = (short)(p2 & 0xFFFF); a[5] = (short)(p2 >> 16);
        a[6] = (short)(p3 & 0xFFFF); a[7] = (short)(p3 >> 16);
      } else if (g == 2) {
        a[0] = (short)f2bf(cdw[t * 4 + 3]);
      }
      a1 = a;
    }

    // --- C-init: acc = staged sum + bSum ---
    f32x4 acc[4];
#pragma unroll
    for (int nt = 0; nt < 4; ++nt)
#pragma unroll
      for (int j = 0; j < 4; ++j) {
        const int row = g * 4 + j, col = t + 16 * nt;
        acc[nt][j] = bf2f(xw[row * XS + col]) + bS_r[nt];
      }
    // --- layer-1 MFMA (ea + radial), K=32 ---
#pragma unroll
    for (int nt = 0; nt < 4; ++nt) {
      const short8 b = *reinterpret_cast<const short8*>(&S.Bea[(t + 16 * nt) * 40 + g * 8]);
      acc[nt] = __builtin_amdgcn_mfma_f32_16x16x32_bf16(a1, b, acc[nt], 0, 0, 0);
    }
#pragma unroll
    for (int nt = 0; nt < 4; ++nt) {
      const unsigned int pk01 = pack2bf(fmaxf(acc[nt][0], 0.f), fmaxf(acc[nt][1], 0.f));
      const unsigned int pk23 = pack2bf(fmaxf(acc[nt][2], 0.f), fmaxf(acc[nt][3], 0.f));
      xw[(g * 4 + 0) * XS + t + 16 * nt] = (unsigned short)(pk01 & 0xFFFF);
      xw[(g * 4 + 1) * XS + t + 16 * nt] = (unsigned short)(pk01 >> 16);
      xw[(g * 4 + 2) * XS + t + 16 * nt] = (unsigned short)(pk23 & 0xFFFF);
      xw[(g * 4 + 3) * XS + t + 16 * nt] = (unsigned short)(pk23 >> 16);
    }
    // --- layer-2 MFMA: m = relu(t1 @ We2 + be2) ---
    short8 A2[2];
#pragma unroll
    for (int kt = 0; kt < 2; ++kt)
      A2[kt] = *reinterpret_cast<const short8*>(&xw[t * XS + kt * 32 + g * 8]);
    f32x4 m2[4];
#pragma unroll
    for (int nt = 0; nt < 4; ++nt) {
      f32x4 c;
      c[0] = be2_r[nt]; c[1] = be2_r[nt]; c[2] = be2_r[nt]; c[3] = be2_r[nt];
#pragma unroll
      for (int kt = 0; kt < 2; ++kt) {
        const short8 b = *reinterpret_cast<const short8*>(
            &S.We2t[(t + 16 * nt) * XS + kt * 32 + g * 8]);
        c = __builtin_amdgcn_mfma_f32_16x16x32_bf16(A2[kt], b, c, 0, 0, 0);
      }
#pragma unroll
      for (int j = 0; j < 4; ++j) c[j] = fmaxf(c[j], 0.f);
      m2[nt] = c;
    }
#pragma unroll
    for (int nt = 0; nt < 4; ++nt) {
      const unsigned int pk01 = pack2bf(m2[nt][0], m2[nt][1]);
      const unsigned int pk23 = pack2bf(m2[nt][2], m2[nt][3]);
      xw[(g * 4 + 0) * XS + t + 16 * nt] = (unsigned short)(pk01 & 0xFFFF);
      xw[(g * 4 + 1) * XS + t + 16 * nt] = (unsigned short)(pk01 >> 16);
      xw[(g * 4 + 2) * XS + t + 16 * nt] = (unsigned short)(pk23 & 0xFFFF);
      xw[(g * 4 + 3) * XS + t + 16 * nt] = (unsigned short)(pk23 >> 16);
    }

    // --- coord MLP MFMA: p = relu(m @ Wc1 + bc1) ---
    short8 A3[2];
#pragma unroll
    for (int kt = 0; kt < 2; ++kt)
      A3[kt] = *reinterpret_cast<const short8*>(&xw[t * XS + kt * 32 + g * 8]);
    float sv[4];
#pragma unroll
    for (int j = 0; j < 4; ++j) sv[j] = 0.f;
#pragma unroll
    for (int nt = 0; nt < 4; ++nt) {
      f32x4 c;
      c[0] = bc1_r[nt]; c[1] = bc1_r[nt]; c[2] = bc1_r[nt]; c[3] = bc1_r[nt];
#pragma unroll
      for (int kt = 0; kt < 2; ++kt) {
        const short8 b = *reinterpret_cast<const short8*>(
            &S.Wc1t[(t + 16 * nt) * XS + kt * 32 + g * 8]);
        c = __builtin_amdgcn_mfma_f32_16x16x32_bf16(A3[kt], b, c, 0, 0, 0);
      }
#pragma unroll
      for (int j = 0; j < 4; ++j) sv[j] = fmaf(fmaxf(c[j], 0.f), wc2_r[nt], sv[j]);
    }
#pragma unroll
    for (int d = 1; d < 16; d <<= 1)
#pragma unroll
      for (int j = 0; j < 4; ++j) sv[j] += __shfl_xor(sv[j], d, 64);
#pragma unroll
    for (int j = 0; j < 4; ++j) sv[j] += bc2v;
#pragma unroll
    for (int j = 0; j < 4; ++j)
      if (t == 0) cdw[(g * 4 + j) * 4 + 3] = sv[j];

    // --- run-compressed agg_m (lane owns column `lane`, 16 sorted rows) ---
    {
      float accm = 0.f;
#pragma unroll
      for (int r = 0; r < 16; ++r) {
        const int rIr = idxw[r];
        const bool valid = (e0 + r) < E;
        if (valid) accm += bf2f(xw[r * XS + lane]);
        const bool closes = (r == 15) || ((e0 + r + 1) >= E) || (idxw[r + 1] != rIr);
        if (valid && closes) {
          atomAddF(&agg_m[(size_t)rIr * 64 + lane], accm);
          accm = 0.f;
        }
      }
    }
    // --- run-compressed agg_x (lanes 0..2) ---
    if (lane < 3) {
      float accx = 0.f;
#pragma unroll
      for (int r = 0; r < 16; ++r) {
        const int rIr = idxw[r];
        const bool valid = (e0 + r) < E;
        if (valid) accx += cdw[r * 4 + lane] * cdw[r * 4 + 3];
        const bool closes = (r == 15) || ((e0 + r + 1) >= E) || (idxw[r + 1] != rIr);
        if (valid && closes) {
          atomAddF(&agg_x[(size_t)rIr * 3 + lane], accx);
          accx = 0.f;
        }
      }
    }
  }
}
#undef XS

// ---------------- k_node (MFMA, folded weights) ----------------
struct NodeLds {
  unsigned short Wn1bT[64 * 72];
  unsigned short WnoT[64 * 72];
  unsigned short x[4][32 * 72];
};

__global__ __launch_bounds__(256, 4) void k_node(
    const unsigned short* __restrict__ nfb, const float* __restrict__ agg_m,
    const float* __restrict__ agg_x, const int* __restrict__ deg,
    const float* __restrict__ co, const float* __restrict__ WF1,
    const float* __restrict__ Wn1, const float* __restrict__ Wno,
    const float* __restrict__ bn1f, const float* __restrict__ bno,
    float* __restrict__ out, float* __restrict__ co_out, int N) {
  __shared__ NodeLds S;
  const int tid = threadIdx.x;
  for (int i = tid; i < 4096; i += 256) {
    const int k = i >> 6, n = i & 63;
    S.Wn1bT[n * 72 + k] = f2bf(Wn1[(64 + k) * 64 + n]);
    S.WnoT[n * 72 + k] = f2bf(Wno[k * 64 + n]);
  }
  __syncthreads();
  const int w = tid >> 6, lane = tid & 63;
  const int g = lane >> 4, t = lane & 15;

  short8 fW1[4];
  float b1_r[4], bo_r[4];
#pragma unroll
  for (int nt = 0; nt < 4; ++nt) {
    const int n = t + 16 * nt;
    short8 a;
#pragma unroll
    for (int j = 0; j < 8; ++j) a[j] = (short)f2bf(WF1[(g * 8 + j) * 64 + n]);
    fW1[nt] = a;
    b1_r[nt] = bn1f[n];
    bo_r[nt] = bno[n];
  }

  unsigned short* xw = &S.x[w][0];
  const int ngroups = (N + 31) >> 5;
  const int GS = gridDim.x * 4;

  for (int grp = blockIdx.x * 4 + w; grp < ngroups; grp += GS) {
    const int base = grp * 32;
    short8 A1[2], Aa[2][2];
#pragma unroll
    for (int mt = 0; mt < 2; ++mt) {
      int node = base + t + 16 * mt;
      if (node >= N) node = N - 1;
      A1[mt] = *reinterpret_cast<const short8*>(nfb + (size_t)node * 32 + g * 8);
#pragma unroll
      for (int kt = 0; kt < 2; ++kt) {
        const f32x4 v0 = *reinterpret_cast<const f32x4*>(
            agg_m + (size_t)node * 64 + kt * 32 + g * 8);
        const f32x4 v1 = *reinterpret_cast<const f32x4*>(
            agg_m + (size_t)node * 64 + kt * 32 + g * 8 + 4);
        const unsigned int p0 = pack2bf(v0[0], v0[1]);
        const unsigned int p1 = pack2bf(v0[2], v0[3]);
        const unsigned int p2 = pack2bf(v1[0], v1[1]);
        const unsigned int p3 = pack2bf(v1[2], v1[3]);
        short8 a;
        a[0] = (short)(p0 & 0xFFFF); a[1] = (short)(p0 >> 16);
        a[2] = (short)(p1 & 0xFFFF); a[3] = (short)(p1 >> 16);
        a[4] = (short)(p2 & 0xFFFF); a[5] = (short)(p2 >> 16);
        a[6] = (short)(p3 & 0xFFFF); a[7] = (short)(p3 >> 16);
        Aa[mt][kt] = a;
      }
    }
    f32x4 acc[2][4];
#pragma unroll
    for (int mt = 0; mt < 2; ++mt)
#pragma unroll
      for (int nt = 0; nt < 4; ++nt) {
        const int n = t + 16 * nt;
        f32x4 c;
        c[0] = b1_r[nt]; c[1] = b1_r[nt]; c[2] = b1_r[nt]; c[3] = b1_r[nt];
        c = __builtin_amdgcn_mfma_f32_16x16x32_bf16(A1[mt], fW1[nt], c, 0, 0, 0);
#pragma unroll
        for (int kt = 0; kt < 2; ++kt) {
          const short8 b = *reinterpret_cast<const short8*>(
              &S.Wn1bT[n * 72 + kt * 32 + g * 8]);
          c = __builtin_amdgcn_mfma_f32_16x16x32_bf16(Aa[mt][kt], b, c, 0, 0, 0);
        }
        acc[mt][nt] = c;
      }
#pragma unroll
    for (int mt = 0; mt < 2; ++mt)
#pragma unroll
      for (int nt = 0; nt < 4; ++nt)
#pragma unroll
        for (int j = 0; j < 4; ++j)
          xw[(g * 4 + j + 16 * mt) * 72 + t + 16 * nt] =
              f2bf(fmaxf(acc[mt][nt][j], 0.f));
    short8 A2[2][2];
#pragma unroll
    for (int mt = 0; mt < 2; ++mt)
#pragma unroll
      for (int kt = 0; kt < 2; ++kt)
        A2[mt][kt] = *reinterpret_cast<const short8*>(
            &S.x[w][(t + 16 * mt) * 72 + kt * 32 + g * 8]);
#pragma unroll
    for (int mt = 0; mt < 2; ++mt)
#pragma unroll
      for (int nt = 0; nt < 4; ++nt) {
        const int n = t + 16 * nt;
        f32x4 c;
        c[0] = bo_r[nt]; c[1] = bo_r[nt]; c[2] = bo_r[nt]; c[3] = bo_r[nt];
#pragma unroll
        for (int kt = 0; kt < 2; ++kt) {
          const short8 b = *reinterpret_cast<const short8*>(
              &S.WnoT[n * 72 + kt * 32 + g * 8]);
          c = __builtin_amdgcn_mfma_f32_16x16x32_bf16(A2[mt][kt], b, c, 0, 0, 0);
        }
#pragma unroll
        for (int j = 0; j < 4; ++j) {
          const int node = base + g * 4 + j + 16 * mt;
          if (node < N) out[(size_t)node * 64 + n] = c[j];
        }
      }
    if (lane < 32) {
      const int node = base + lane;
      if (node < N) {
        const float dv = fmaxf((float)deg[node], 1.f);
#pragma unroll
        for (int d = 0; d < 3; ++d)
          co_out[(size_t)node * 3 + d] =
              co[(size_t)node * 3 + d] + agg_x[(size_t)node * 3 + d] / dv;
      }
    }
  }
}

extern "C" void kernel_launch(void* const* d_in, const int* in_sizes, int n_in,
                              void* d_out, int out_size, void* d_ws, size_t ws_size,
                              hipStream_t stream) {
  const float* nf = (const float*)d_in[0];
  const float* ea = (const float*)d_in[1];
  const float* co = (const float*)d_in[2];
  const int* ei = (const int*)d_in[3];
  const float* W_in = (const float*)d_in[4];
  const float* b_in = (const float*)d_in[5];
  const float* W_out = (const float*)d_in[6];
  const float* b_out = (const float*)d_in[7];
  const float* We1 = (const float*)d_in[8];
  const float* be1 = (const float*)d_in[9];
  const float* We2 = (const float*)d_in[10];
  const float* be2 = (const float*)d_in[11];
  const float* Wn1 = (const float*)d_in[12];
  const float* bn1 = (const float*)d_in[13];
  const float* Wn2 = (const float*)d_in[14];
  const float* bn2 = (const float*)d_in[15];
  const float* Wc1 = (const float*)d_in[16];
  const float* bc1 = (const float*)d_in[17];
  const float* Wc2 = (const float*)d_in[18];
  const float* bc2 = (const float*)d_in[19];

  const int N = in_sizes[0] / 32;
  const int E = in_sizes[1] / 16;

  float* ws = (float*)d_ws;
  float* agg_m = ws;                                   // N*64
  float* agg_x = agg_m + (size_t)N * 64;               // N*3
  int* deg = (int*)(agg_x + (size_t)N * 3);            // N
  float* WA = (float*)(deg + N);                       // 2048
  float* WB = WA + 2048;
  float* WF1 = WB + 2048;
  float* Wno = WF1 + 2048;                             // 4096
  float* bSum = Wno + 4096;                            // 64
  float* bn1f = bSum + 64;
  float* bno = bn1f + 64;
  int* rowNext = (int*)(bno + 64);                     // N
  int* bsumBuf = rowNext + N;                          // 512
  uintptr_t pp = (uintptr_t)(bsumBuf + 512);
  pp = (pp + 15) & ~(uintptr_t)15;
  f32x4* cdr = (f32x4*)pp;                             // E (16B aligned)
  unsigned long long* srt8 = (unsigned long long*)(cdr + E);  // E
  unsigned short* nfb = (unsigned short*)(srt8 + E);   // N*32

  float* outp = (float*)d_out;
  float* co_out = outp + (size_t)N * 64;
  unsigned short* gA = (unsigned short*)d_out;         // N*64 bf16 (scratch)
  unsigned short* gB = gA + (size_t)N * 64;            // N*64 bf16

  const int nb = (N + 255) / 256;

  k_prep<<<1031, 256, 0, stream>>>(nf, W_in, b_in, We1, be1, Wn1, bn1, Wn2,
                                   bn2, W_out, b_out, nfb, WA, WB, WF1, Wno,
                                   bSum, bn1f, bno, agg_m, N);
  k_gab<<<2048 + 512, 256, 0, stream>>>(nf, WA, WB, gA, gB, ei, deg, N, E, 2048);
  k_scanA<<<nb, 256, 0, stream>>>(deg, rowNext, bsumBuf, N);
  k_scanC<<<nb, 256, 0, stream>>>(rowNext, bsumBuf, N);
  k_scatter<<<1024, 256, 0, stream>>>(ei, co, rowNext, srt8, cdr, E);
  k_edge<<<1024, 256, 0, stream>>>(gA, gB, ea, cdr, srt8, We1, bSum, be2, We2,
                                   bc1, Wc1, Wc2, bc2, agg_m, agg_x, E);
  k_node<<<1024, 256, 0, stream>>>(nfb, agg_m, agg_x, deg, co, WF1, Wn1, Wno,
                                   bn1f, bno, outp, co_out, N);
}